// Round 7
// baseline (5316.800 us; speedup 1.0000x reference)
//
#include <hip/hip_runtime.h>

#define STEPS 96
#define HDIM 4096
#define IDIM 1024

// ---------------- fast variant geometry ----------------
#define FBLOCKS 512
#define FTHREADS 1024
#define FWAVES 16
#define FRPB 8                      // rows per block
#define FGROUPS 8
#define FBPG (FBLOCKS / FGROUPS)    // 64

// ---------------- safe (fallback) geometry ----------------
#define SBLOCKS 256
#define STHREADS 1024
#define SWAVES 16
#define SRPB 16

#define PIN(x) asm volatile("" : "+v"(x))

// ---------- bf16 helpers ----------
__device__ inline unsigned short f2bf(float f) {
  unsigned u = __float_as_uint(f);
  u += 0x7fffu + ((u >> 16) & 1u);
  return (unsigned short)(u >> 16);
}
__device__ inline unsigned pack2(float a, float b) {
  return (unsigned)f2bf(a) | ((unsigned)f2bf(b) << 16);
}
__device__ inline float blo(unsigned p) { return __uint_as_float(p << 16); }
__device__ inline float bhi(unsigned p) { return __uint_as_float(p & 0xffff0000u); }

__device__ inline float wave_reduce(float v) {
#pragma unroll
  for (int off = 32; off > 0; off >>= 1) v += __shfl_xor(v, off);
  return v;
}

// ======================= FAST KERNEL =======================
struct ParamsF {
  const float *x, *Wih0, *bih0, *Whh0, *bhh0, *Wih1, *bih1, *Whh1, *bhh1, *Wfc, *bfc;
  unsigned short *h0g, *h1g;  // bf16[HDIM] each, single-buffered
  unsigned *leaf, *root, *flag;
  float *out;
};

__device__ inline void grid_barrier_f(const ParamsF& p, unsigned gen) {
  __syncthreads();
  if (threadIdx.x == 0) {
    __threadfence();
    const int g = blockIdx.x & (FGROUPS - 1);
    unsigned prev = __hip_atomic_fetch_add(p.leaf + g * 32, 1u, __ATOMIC_RELAXED,
                                           __HIP_MEMORY_SCOPE_AGENT);
    if (prev == gen * FBPG - 1) {
      unsigned r = __hip_atomic_fetch_add(p.root, 1u, __ATOMIC_RELAXED,
                                          __HIP_MEMORY_SCOPE_AGENT);
      if (r == gen * FGROUPS - 1) {
        __hip_atomic_store(p.flag, gen, __ATOMIC_RELEASE, __HIP_MEMORY_SCOPE_AGENT);
      }
    }
    while (__hip_atomic_load(p.flag, __ATOMIC_RELAXED, __HIP_MEMORY_SCOPE_AGENT) < gen) {
      __builtin_amdgcn_s_sleep(1);
    }
    __threadfence();
  }
  __syncthreads();
}

__global__ void __launch_bounds__(FTHREADS, 4) rnn_fast(ParamsF p) {
  __shared__ unsigned whh1L[FRPB * (HDIM / 2)];  // 64 KB, linear u32-pair packing
  __shared__ unsigned wfcL[HDIM / 2];            // 8 KB
  __shared__ float win[IDIM + STEPS];            // 4.4 KB
  __shared__ float red1[FWAVES];
  __shared__ float b0L[FRPB], b1L[FRPB];
  __shared__ float bfcL;

  const int tid = threadIdx.x, lane = tid & 63, wv = tid >> 6, blk = blockIdx.x;
  const int r = wv >> 1, hf = wv & 1;  // wave -> (row, column-half)
  const int gr = blk * FRPB + r;

  // ---- setup: LDS-resident weights ----
  for (int idx = tid; idx < FRPB * (HDIM / 2); idx += FTHREADS) {
    const int rr = idx >> 11, i = idx & (HDIM / 2 - 1);
    float2 f = *reinterpret_cast<const float2*>(
        p.Whh1 + (size_t)(blk * FRPB + rr) * HDIM + 2 * i);
    whh1L[idx] = pack2(f.x, f.y);
  }
  for (int i = tid; i < HDIM / 2; i += FTHREADS) {
    float2 f = *reinterpret_cast<const float2*>(p.Wfc + 2 * i);
    wfcL[i] = pack2(f.x, f.y);
  }
  for (int i = tid; i < IDIM; i += FTHREADS) win[i] = p.x[i];
  if (tid < FRPB) {
    b0L[tid] = p.bih0[blk * FRPB + tid] + p.bhh0[blk * FRPB + tid];
    b1L[tid] = p.bih1[blk * FRPB + tid] + p.bhh1[blk * FRPB + tid];
  }
  if (tid == 0) bfcL = p.bfc[0];

  // ---- setup: register-resident packed weights (36 u32), pinned ----
  unsigned w_ih0[4], w_hh0[16], w_ih1[16];
#pragma unroll
  for (int j = 0; j < 4; ++j) {
    float2 g = *reinterpret_cast<const float2*>(
        p.Wih0 + (size_t)gr * IDIM + hf * 512 + j * 128 + lane * 2);
    w_ih0[j] = pack2(g.x, g.y);
    PIN(w_ih0[j]);
  }
#pragma unroll
  for (int j = 0; j < 8; ++j) {
    float4 f = *reinterpret_cast<const float4*>(
        p.Whh0 + (size_t)gr * HDIM + hf * 2048 + j * 256 + lane * 4);
    w_hh0[2 * j] = pack2(f.x, f.y);
    w_hh0[2 * j + 1] = pack2(f.z, f.w);
    PIN(w_hh0[2 * j]); PIN(w_hh0[2 * j + 1]);
    f = *reinterpret_cast<const float4*>(
        p.Wih1 + (size_t)gr * HDIM + hf * 2048 + j * 256 + lane * 4);
    w_ih1[2 * j] = pack2(f.x, f.y);
    w_ih1[2 * j + 1] = pack2(f.z, f.w);
    PIN(w_ih1[2 * j]); PIN(w_ih1[2 * j + 1]);
  }

  __syncthreads();

  const unsigned* h0u = reinterpret_cast<const unsigned*>(p.h0g) + hf * 1024 + lane * 2;
  const unsigned* h1u = reinterpret_cast<const unsigned*>(p.h1g) + hf * 1024 + lane * 2;
  const unsigned* wl = whh1L + r * (HDIM / 2) + hf * 1024 + lane * 2;

  float p1 = 0.f;  // carried per-lane partial of Whh0 . h0_old
  unsigned gen = 0;

  for (int t = 0; t < STEPS; ++t) {
    // ---- phase 1: h0 = tanh(Wih0 @ win[t:] + carried + bias) ----
    float a1 = p1;
#pragma unroll
    for (int j = 0; j < 4; ++j) {
      const int c = t + hf * 512 + j * 128 + lane * 2;
      a1 += win[c] * blo(w_ih0[j]) + win[c + 1] * bhi(w_ih0[j]);
    }
    a1 = wave_reduce(a1);
    if (lane == 0) red1[wv] = a1;

    // ---- slot 2 (pre-barrier): Whh1 @ h1_old (LDS weights, bf16 global h) ----
    float a2 = 0.f;
#pragma unroll
    for (int j = 0; j < 8; ++j) {
      uint2 hv = *reinterpret_cast<const uint2*>(h1u + j * 128);
      uint2 wvv = *reinterpret_cast<const uint2*>(wl + j * 128);
      a2 += blo(wvv.x) * blo(hv.x) + bhi(wvv.x) * bhi(hv.x) +
            blo(wvv.y) * blo(hv.y) + bhi(wvv.y) * bhi(hv.y);
    }

    __syncthreads();  // red1 complete
    if ((tid & 127) == 0) {
      const int rr = tid >> 7;
      float s = red1[2 * rr] + red1[2 * rr + 1] + b0L[rr];
      p.h0g[blk * FRPB + rr] = f2bf(tanhf(s));
    }
    grid_barrier_f(p, ++gen);  // h0 globally complete

    // ---- phase 2: += Wih1 @ h0 ; next step's Whh0 @ h0 partial ----
    float q1 = 0.f;
#pragma unroll
    for (int j = 0; j < 8; ++j) {
      uint2 hv = *reinterpret_cast<const uint2*>(h0u + j * 128);
      a2 += blo(w_ih1[2 * j]) * blo(hv.x) + bhi(w_ih1[2 * j]) * bhi(hv.x) +
            blo(w_ih1[2 * j + 1]) * blo(hv.y) + bhi(w_ih1[2 * j + 1]) * bhi(hv.y);
      q1 += blo(w_hh0[2 * j]) * blo(hv.x) + bhi(w_hh0[2 * j]) * bhi(hv.x) +
            blo(w_hh0[2 * j + 1]) * blo(hv.y) + bhi(w_hh0[2 * j + 1]) * bhi(hv.y);
    }
    a2 = wave_reduce(a2);
    if (lane == 0) red1[wv] = a2;
    p1 = q1;
    __syncthreads();
    if ((tid & 127) == 0) {
      const int rr = tid >> 7;
      float s = red1[2 * rr] + red1[2 * rr + 1] + b1L[rr];
      p.h1g[blk * FRPB + rr] = f2bf(tanhf(s));
    }
    grid_barrier_f(p, ++gen);  // h1 globally complete

    // ---- phase 3: y = Wfc @ h1 + b_fc (redundant per block), append ----
    {
      uint2 hv = *reinterpret_cast<const uint2*>(
          reinterpret_cast<const unsigned*>(p.h1g) + 2 * tid);
      uint2 wf = *reinterpret_cast<const uint2*>(wfcL + 2 * tid);
      float part = blo(wf.x) * blo(hv.x) + bhi(wf.x) * bhi(hv.x) +
                   blo(wf.y) * blo(hv.y) + bhi(wf.y) * bhi(hv.y);
      part = wave_reduce(part);
      if (lane == 0) red1[wv] = part;
    }
    __syncthreads();
    if (tid == 0) {
      float y = bfcL;
#pragma unroll
      for (int i = 0; i < FWAVES; ++i) y += red1[i];
      win[IDIM + t] = y;
      if (blk == 0) p.out[t] = y;
    }
    __syncthreads();
  }
}

// ======================= SAFE FALLBACK (R6, known-good) =======================
struct ParamsS {
  const float *x, *Wih0, *bih0, *Whh0, *bhh0, *Wih1, *bih1, *Whh1, *bhh1, *Wfc, *bfc;
  float *h0, *h1;
  unsigned *leaf, *root, *flag;
  float *out;
};

__device__ inline void grid_barrier_s(const ParamsS& p, unsigned gen) {
  __syncthreads();
  if (threadIdx.x == 0) {
    __threadfence();
    const int g = blockIdx.x & 7;
    unsigned prev = __hip_atomic_fetch_add(p.leaf + g * 32, 1u, __ATOMIC_RELAXED,
                                           __HIP_MEMORY_SCOPE_AGENT);
    if (prev == gen * (SBLOCKS / 8) - 1) {
      unsigned r = __hip_atomic_fetch_add(p.root, 1u, __ATOMIC_RELAXED,
                                          __HIP_MEMORY_SCOPE_AGENT);
      if (r == gen * 8 - 1) {
        __hip_atomic_store(p.flag, gen, __ATOMIC_RELEASE, __HIP_MEMORY_SCOPE_AGENT);
      }
    }
    while (__hip_atomic_load(p.flag, __ATOMIC_RELAXED, __HIP_MEMORY_SCOPE_AGENT) < gen) {
      __builtin_amdgcn_s_sleep(1);
    }
    __threadfence();
  }
  __syncthreads();
}

__global__ void __launch_bounds__(STHREADS) rnn_safe(ParamsS p) {
  __shared__ unsigned whh1[SRPB * (HDIM / 2)];
  __shared__ float win[IDIM + STEPS];
  __shared__ float hstage[HDIM];
  __shared__ float red[SWAVES];

  const int tid = threadIdx.x, lane = tid & 63, wv = tid >> 6, blk = blockIdx.x;
  const int row = blk * SRPB + wv;

  for (int rr = 0; rr < SRPB; ++rr) {
    const float* src = p.Whh1 + (size_t)(blk * SRPB + rr) * HDIM;
    for (int u = tid; u < HDIM / 2; u += STHREADS) {
      float2 f = *reinterpret_cast<const float2*>(src + 2 * u);
      whh1[rr * (HDIM / 2) + u] = pack2(f.x, f.y);
    }
  }
  for (int i = tid; i < HDIM; i += STHREADS) hstage[i] = 0.f;
  for (int i = tid; i < IDIM; i += STHREADS) win[i] = p.x[i];

  unsigned w_ih0[8];
#pragma unroll
  for (int j = 0; j < 8; ++j) {
    const float* s = p.Wih0 + (size_t)row * IDIM + j * 128 + lane;
    w_ih0[j] = pack2(s[0], s[64]);
    PIN(w_ih0[j]);
  }
  unsigned w_hh0[32], w_ih1[32];
#pragma unroll
  for (int j = 0; j < 16; ++j) {
    float4 f;
    f = *reinterpret_cast<const float4*>(p.Whh0 + (size_t)row * HDIM + j * 256 + lane * 4);
    w_hh0[2 * j] = pack2(f.x, f.y); w_hh0[2 * j + 1] = pack2(f.z, f.w);
    PIN(w_hh0[2 * j]); PIN(w_hh0[2 * j + 1]);
    f = *reinterpret_cast<const float4*>(p.Wih1 + (size_t)row * HDIM + j * 256 + lane * 4);
    w_ih1[2 * j] = pack2(f.x, f.y); w_ih1[2 * j + 1] = pack2(f.z, f.w);
    PIN(w_ih1[2 * j]); PIN(w_ih1[2 * j + 1]);
  }
  unsigned wfcp[2];
  {
    float4 f = *reinterpret_cast<const float4*>(p.Wfc + tid * 4);
    wfcp[0] = pack2(f.x, f.y); wfcp[1] = pack2(f.z, f.w);
    PIN(wfcp[0]); PIN(wfcp[1]);
  }
  float bias0 = p.bih0[row] + p.bhh0[row];
  float bias1 = p.bih1[row] + p.bhh1[row];
  float bfc = p.bfc[0];
  PIN(bias0); PIN(bias1); PIN(bfc);

  __syncthreads();

  float p1 = 0.f;
  unsigned gen = 0;

  for (int t = 0; t < STEPS; ++t) {
    float a1 = p1;
#pragma unroll
    for (int j = 0; j < 8; ++j) {
      float v0 = win[t + j * 128 + lane];
      float v1 = win[t + j * 128 + 64 + lane];
      a1 += v0 * blo(w_ih0[j]) + v1 * bhi(w_ih0[j]);
    }
    a1 = wave_reduce(a1);
    if (lane == 0) p.h0[row] = tanhf(a1 + bias0);

    float a2 = 0.f;
    {
      const unsigned* wlp = whh1 + wv * (HDIM / 2);
#pragma unroll
      for (int j = 0; j < 16; ++j) {
        float4 v = *reinterpret_cast<const float4*>(hstage + j * 256 + lane * 4);
        unsigned c0 = wlp[j * 128 + lane * 2], c1 = wlp[j * 128 + lane * 2 + 1];
        a2 += v.x * blo(c0) + v.y * bhi(c0) + v.z * blo(c1) + v.w * bhi(c1);
      }
    }

    grid_barrier_s(p, ++gen);

    {
      float4 v = *reinterpret_cast<const float4*>(p.h0 + tid * 4);
      *reinterpret_cast<float4*>(hstage + tid * 4) = v;
    }
    __syncthreads();
    float q1 = 0.f;
#pragma unroll
    for (int j = 0; j < 16; ++j) {
      float4 v = *reinterpret_cast<const float4*>(hstage + j * 256 + lane * 4);
      a2 += v.x * blo(w_ih1[2 * j]) + v.y * bhi(w_ih1[2 * j]) +
            v.z * blo(w_ih1[2 * j + 1]) + v.w * bhi(w_ih1[2 * j + 1]);
      q1 += v.x * blo(w_hh0[2 * j]) + v.y * bhi(w_hh0[2 * j]) +
            v.z * blo(w_hh0[2 * j + 1]) + v.w * bhi(w_hh0[2 * j + 1]);
    }
    a2 = wave_reduce(a2);
    if (lane == 0) p.h1[row] = tanhf(a2 + bias1);
    p1 = q1;

    grid_barrier_s(p, ++gen);

    {
      float4 v = *reinterpret_cast<const float4*>(p.h1 + tid * 4);
      *reinterpret_cast<float4*>(hstage + tid * 4) = v;
      float part = v.x * blo(wfcp[0]) + v.y * bhi(wfcp[0]) +
                   v.z * blo(wfcp[1]) + v.w * bhi(wfcp[1]);
      part = wave_reduce(part);
      if (lane == 0) red[wv] = part;
    }
    __syncthreads();
    if (tid == 0) {
      float y = bfc;
#pragma unroll
      for (int i = 0; i < SWAVES; ++i) y += red[i];
      win[IDIM + t] = y;
      if (blk == 0) p.out[t] = y;
    }
    __syncthreads();
  }
}

// ======================= LAUNCH =======================
extern "C" void kernel_launch(void* const* d_in, const int* in_sizes, int n_in,
                              void* d_out, int out_size, void* d_ws, size_t ws_size,
                              hipStream_t stream) {
  const float* x = (const float*)d_in[0];
  const float* Wih0 = (const float*)d_in[1];
  const float* bih0 = (const float*)d_in[2];
  const float* Whh0 = (const float*)d_in[3];
  const float* bhh0 = (const float*)d_in[4];
  const float* Wih1 = (const float*)d_in[5];
  const float* bih1 = (const float*)d_in[6];
  const float* Whh1 = (const float*)d_in[7];
  const float* bhh1 = (const float*)d_in[8];
  const float* Wfc = (const float*)d_in[9];
  const float* bfc = (const float*)d_in[10];
  float* out = (float*)d_out;

  char* ws = (char*)d_ws;
  // layout: [0,8K) h0g bf16 | [8K,16K) h1g bf16 | [16K,+1.3K) fast barrier |
  //         [20K,52K) safe f32 h bufs | [56K,+1.3K) safe barrier
  unsigned short* h0g = (unsigned short*)ws;
  unsigned short* h1g = (unsigned short*)(ws + 8 * 1024);
  unsigned* fbar = (unsigned*)(ws + 16 * 1024);
  float* hs = (float*)(ws + 20 * 1024);
  unsigned* sbar = (unsigned*)(ws + 56 * 1024);

  hipMemsetAsync(d_ws, 0, 64 * 1024, stream);  // zero h state + both barrier states

  int nb = 0;
  hipError_t err = hipOccupancyMaxActiveBlocksPerMultiprocessor(&nb, rnn_fast, FTHREADS, 0);

  if (err == hipSuccess && nb >= 2) {
    ParamsF p;
    p.x = x; p.Wih0 = Wih0; p.bih0 = bih0; p.Whh0 = Whh0; p.bhh0 = bhh0;
    p.Wih1 = Wih1; p.bih1 = bih1; p.Whh1 = Whh1; p.bhh1 = bhh1;
    p.Wfc = Wfc; p.bfc = bfc;
    p.h0g = h0g; p.h1g = h1g;
    p.leaf = fbar; p.root = fbar + 8 * 32; p.flag = fbar + 8 * 32 + 32;
    p.out = out;
    void* args[] = {&p};
    hipLaunchCooperativeKernel(reinterpret_cast<void*>(&rnn_fast),
                               dim3(FBLOCKS), dim3(FTHREADS), args, 0, stream);
  } else {
    ParamsS p;
    p.x = x; p.Wih0 = Wih0; p.bih0 = bih0; p.Whh0 = Whh0; p.bhh0 = bhh0;
    p.Wih1 = Wih1; p.bih1 = bih1; p.Whh1 = Whh1; p.bhh1 = bhh1;
    p.Wfc = Wfc; p.bfc = bfc;
    p.h0 = hs; p.h1 = hs + HDIM;
    p.leaf = sbar; p.root = sbar + 8 * 32; p.flag = sbar + 8 * 32 + 32;
    p.out = out;
    void* args[] = {&p};
    hipLaunchCooperativeKernel(reinterpret_cast<void*>(&rnn_safe),
                               dim3(SBLOCKS), dim3(STHREADS), args, 0, stream);
  }
}

// Round 8
// 5307.515 us; speedup vs baseline: 1.0017x; 1.0017x over previous
//
#include <hip/hip_runtime.h>

#define STEPS 96
#define HDIM 4096
#define IDIM 1024

// ---------------- fast geometry: 512 blocks x 512 threads, 2 blocks/CU ----------------
#define FBLOCKS 512
#define FTHREADS 512
#define FWAVES 8
#define FRPB 8                      // rows per block (1 per wave)
#define FGROUPS 8
#define FBPG (FBLOCKS / FGROUPS)    // 64

// ---------------- safe fallback geometry (R6, known-good) ----------------
#define SBLOCKS 256
#define STHREADS 1024
#define SWAVES 16
#define SRPB 16

#define PIN(x) asm volatile("" : "+v"(x))

// ---------- bf16 helpers ----------
__device__ inline unsigned short f2bf(float f) {
  unsigned u = __float_as_uint(f);
  u += 0x7fffu + ((u >> 16) & 1u);
  return (unsigned short)(u >> 16);
}
__device__ inline unsigned pack2(float a, float b) {
  return (unsigned)f2bf(a) | ((unsigned)f2bf(b) << 16);
}
__device__ inline float blo(unsigned p) { return __uint_as_float(p << 16); }
__device__ inline float bhi(unsigned p) { return __uint_as_float(p & 0xffff0000u); }

__device__ inline float wave_reduce(float v) {
#pragma unroll
  for (int off = 32; off > 0; off >>= 1) v += __shfl_xor(v, off);
  return v;
}

// agent-scope coherent (L1/L2-bypassing) accessors — no fences needed around them
__device__ inline unsigned aload(const unsigned* p) {
  return __hip_atomic_load(p, __ATOMIC_RELAXED, __HIP_MEMORY_SCOPE_AGENT);
}
__device__ inline void astore(unsigned* p, unsigned v) {
  __hip_atomic_store(p, v, __ATOMIC_RELAXED, __HIP_MEMORY_SCOPE_AGENT);
}

// ======================= FAST KERNEL =======================
struct ParamsF {
  const float *x, *Wih0, *bih0, *Whh0, *bhh0, *Wih1, *bih1, *Whh1, *bhh1, *Wfc, *bfc;
  unsigned *h0g, *h1g;  // packed bf16 pairs, HDIM/2 u32 each
  unsigned *leaf, *root, *flag;
  float *out;
};

// NO-INVALIDATE grid barrier: per-thread vmcnt drain (write-through atomics reach
// coherence point), relaxed agent atomics for arrive/spin, no __threadfence anywhere
// => L2 contents (weights, scratch) survive across barriers.
__device__ inline void gbar_f(const ParamsF& p, unsigned gen) {
  asm volatile("s_waitcnt vmcnt(0)" ::: "memory");
  __syncthreads();
  if (threadIdx.x == 0) {
    const int g = blockIdx.x & (FGROUPS - 1);
    unsigned prev = __hip_atomic_fetch_add(p.leaf + g * 32, 1u, __ATOMIC_RELAXED,
                                           __HIP_MEMORY_SCOPE_AGENT);
    if (prev == gen * FBPG - 1) {
      unsigned r = __hip_atomic_fetch_add(p.root, 1u, __ATOMIC_RELAXED,
                                          __HIP_MEMORY_SCOPE_AGENT);
      if (r == gen * FGROUPS - 1) {
        __hip_atomic_store(p.flag, gen, __ATOMIC_RELAXED, __HIP_MEMORY_SCOPE_AGENT);
      }
    }
    while (__hip_atomic_load(p.flag, __ATOMIC_RELAXED, __HIP_MEMORY_SCOPE_AGENT) < gen) {
      __builtin_amdgcn_s_sleep(1);
    }
  }
  __syncthreads();
  asm volatile("" ::: "memory");
}

__global__ void __launch_bounds__(FTHREADS, 2) rnn_fast(ParamsF p) {
  __shared__ unsigned whh1L[FRPB * (HDIM / 2)];  // 64 KB: block's 8 W_hh1 rows, bf16 pairs
  __shared__ float win[IDIM + STEPS];            // 4.4 KB sliding window
  __shared__ unsigned hstage[HDIM / 2];          // 8 KB: current h vector, bf16 pairs
  __shared__ float red1[FWAVES];
  __shared__ float b0L[FRPB], b1L[FRPB];
  __shared__ float bfcL;

  const int tid = threadIdx.x, lane = tid & 63, wv = tid >> 6, blk = blockIdx.x;
  const int row = blk * FRPB + wv;  // this wave's row in Wih0/Whh0/Wih1/Whh1

  // ---- setup: LDS weights + window + zero hstage (h1_old = 0 at t=0) ----
  for (int idx = tid; idx < FRPB * (HDIM / 2); idx += FTHREADS) {
    const int rr = idx >> 11, i = idx & (HDIM / 2 - 1);
    float2 f = *reinterpret_cast<const float2*>(
        p.Whh1 + (size_t)(blk * FRPB + rr) * HDIM + 2 * i);
    whh1L[idx] = pack2(f.x, f.y);
  }
  for (int i = tid; i < HDIM / 2; i += FTHREADS) hstage[i] = 0u;
  for (int i = tid; i < IDIM; i += FTHREADS) win[i] = p.x[i];
  if (tid < FRPB) {
    b0L[tid] = p.bih0[blk * FRPB + tid] + p.bhh0[blk * FRPB + tid];
    b1L[tid] = p.bih1[blk * FRPB + tid] + p.bhh1[blk * FRPB + tid];
  }
  if (tid == 0) bfcL = p.bfc[0];

  // ---- setup: 76 pinned weight regs / thread ----
  unsigned w_ih0[8];
#pragma unroll
  for (int j = 0; j < 8; ++j) {
    const float* s = p.Wih0 + (size_t)row * IDIM + j * 128 + lane;
    w_ih0[j] = pack2(s[0], s[64]);
    PIN(w_ih0[j]);
  }
  unsigned w_hh0[32], w_ih1[32];
#pragma unroll
  for (int j = 0; j < 16; ++j) {
    float4 f;
    f = *reinterpret_cast<const float4*>(p.Whh0 + (size_t)row * HDIM + j * 256 + lane * 4);
    w_hh0[2 * j] = pack2(f.x, f.y); w_hh0[2 * j + 1] = pack2(f.z, f.w);
    PIN(w_hh0[2 * j]); PIN(w_hh0[2 * j + 1]);
    f = *reinterpret_cast<const float4*>(p.Wih1 + (size_t)row * HDIM + j * 256 + lane * 4);
    w_ih1[2 * j] = pack2(f.x, f.y); w_ih1[2 * j + 1] = pack2(f.z, f.w);
    PIN(w_ih1[2 * j]); PIN(w_ih1[2 * j + 1]);
  }
  unsigned wfcp[4];
  {
    float4 f = *reinterpret_cast<const float4*>(p.Wfc + tid * 8);
    wfcp[0] = pack2(f.x, f.y); wfcp[1] = pack2(f.z, f.w);
    f = *reinterpret_cast<const float4*>(p.Wfc + tid * 8 + 4);
    wfcp[2] = pack2(f.x, f.y); wfcp[3] = pack2(f.z, f.w);
    PIN(wfcp[0]); PIN(wfcp[1]); PIN(wfcp[2]); PIN(wfcp[3]);
  }

  __syncthreads();

  float p1 = 0.f;  // carried per-lane partial of Whh0 . h0_old (zero at t=0)
  unsigned gen = 0;

  for (int t = 0; t < STEPS; ++t) {
    // ---- phase 1: full-row dot Wih0 @ win[t:] + carried partial ----
    float a1 = p1;
#pragma unroll
    for (int j = 0; j < 8; ++j) {
      a1 += win[t + j * 128 + lane] * blo(w_ih0[j]) +
            win[t + j * 128 + 64 + lane] * bhi(w_ih0[j]);
    }
    a1 = wave_reduce(a1);
    if (lane == 0) red1[wv] = a1;

    // ---- slot 2 (pre-barrier): Whh1 @ h1_old, both operands LDS ----
    float a2 = 0.f;
    {
      const unsigned* wl = whh1L + wv * (HDIM / 2);
#pragma unroll
      for (int j = 0; j < 16; ++j) {
        uint2 hv = *reinterpret_cast<const uint2*>(hstage + j * 128 + lane * 2);
        uint2 wp = *reinterpret_cast<const uint2*>(wl + j * 128 + lane * 2);
        a2 += blo(wp.x) * blo(hv.x) + bhi(wp.x) * bhi(hv.x) +
              blo(wp.y) * blo(hv.y) + bhi(wp.y) * bhi(hv.y);
      }
    }

    __syncthreads();  // red1 complete, hstage(h1_old) fully consumed
    if (tid < FRPB / 2) {
      unsigned pk = pack2(tanhf(red1[2 * tid] + b0L[2 * tid]),
                          tanhf(red1[2 * tid + 1] + b0L[2 * tid + 1]));
      astore(p.h0g + blk * (FRPB / 2) + tid, pk);
    }
    gbar_f(p, ++gen);  // h0 globally visible

    // ---- phase 2: stage h0 -> LDS (coherent loads), then Wih1 @ h0 + next Whh0 partial ----
#pragma unroll
    for (int k = 0; k < (HDIM / 2) / FTHREADS; ++k)
      hstage[tid + k * FTHREADS] = aload(p.h0g + tid + k * FTHREADS);
    __syncthreads();
    float q1 = 0.f;
#pragma unroll
    for (int j = 0; j < 16; ++j) {
      uint2 hv = *reinterpret_cast<const uint2*>(hstage + j * 128 + lane * 2);
      a2 += blo(w_ih1[2 * j]) * blo(hv.x) + bhi(w_ih1[2 * j]) * bhi(hv.x) +
            blo(w_ih1[2 * j + 1]) * blo(hv.y) + bhi(w_ih1[2 * j + 1]) * bhi(hv.y);
      q1 += blo(w_hh0[2 * j]) * blo(hv.x) + bhi(w_hh0[2 * j]) * bhi(hv.x) +
            blo(w_hh0[2 * j + 1]) * blo(hv.y) + bhi(w_hh0[2 * j + 1]) * bhi(hv.y);
    }
    a2 = wave_reduce(a2);
    if (lane == 0) red1[wv] = a2;
    p1 = q1;
    __syncthreads();
    if (tid < FRPB / 2) {
      unsigned pk = pack2(tanhf(red1[2 * tid] + b1L[2 * tid]),
                          tanhf(red1[2 * tid + 1] + b1L[2 * tid + 1]));
      astore(p.h1g + blk * (FRPB / 2) + tid, pk);
    }
    gbar_f(p, ++gen);  // h1 globally visible

    // ---- phase 3: stage h1 -> hstage (doubles as next step's h1_old); FC dot ----
#pragma unroll
    for (int k = 0; k < (HDIM / 2) / FTHREADS; ++k)
      hstage[tid + k * FTHREADS] = aload(p.h1g + tid + k * FTHREADS);
    __syncthreads();
    {
      uint2 ha = *reinterpret_cast<const uint2*>(hstage + tid * 4);
      uint2 hb = *reinterpret_cast<const uint2*>(hstage + tid * 4 + 2);
      float part = blo(wfcp[0]) * blo(ha.x) + bhi(wfcp[0]) * bhi(ha.x) +
                   blo(wfcp[1]) * blo(ha.y) + bhi(wfcp[1]) * bhi(ha.y) +
                   blo(wfcp[2]) * blo(hb.x) + bhi(wfcp[2]) * bhi(hb.x) +
                   blo(wfcp[3]) * blo(hb.y) + bhi(wfcp[3]) * bhi(hb.y);
      part = wave_reduce(part);
      if (lane == 0) red1[wv] = part;
    }
    __syncthreads();
    if (tid == 0) {
      float y = bfcL;
#pragma unroll
      for (int i = 0; i < FWAVES; ++i) y += red1[i];
      win[IDIM + t] = y;
      if (blk == 0) p.out[t] = y;
    }
    __syncthreads();
  }
}

// ======================= SAFE FALLBACK (R6, known-good 5.3ms) =======================
struct ParamsS {
  const float *x, *Wih0, *bih0, *Whh0, *bhh0, *Wih1, *bih1, *Whh1, *bhh1, *Wfc, *bfc;
  float *h0, *h1;
  unsigned *leaf, *root, *flag;
  float *out;
};

__device__ inline void grid_barrier_s(const ParamsS& p, unsigned gen) {
  __syncthreads();
  if (threadIdx.x == 0) {
    __threadfence();
    const int g = blockIdx.x & 7;
    unsigned prev = __hip_atomic_fetch_add(p.leaf + g * 32, 1u, __ATOMIC_RELAXED,
                                           __HIP_MEMORY_SCOPE_AGENT);
    if (prev == gen * (SBLOCKS / 8) - 1) {
      unsigned r = __hip_atomic_fetch_add(p.root, 1u, __ATOMIC_RELAXED,
                                          __HIP_MEMORY_SCOPE_AGENT);
      if (r == gen * 8 - 1) {
        __hip_atomic_store(p.flag, gen, __ATOMIC_RELEASE, __HIP_MEMORY_SCOPE_AGENT);
      }
    }
    while (__hip_atomic_load(p.flag, __ATOMIC_RELAXED, __HIP_MEMORY_SCOPE_AGENT) < gen) {
      __builtin_amdgcn_s_sleep(1);
    }
    __threadfence();
  }
  __syncthreads();
}

__global__ void __launch_bounds__(STHREADS) rnn_safe(ParamsS p) {
  __shared__ unsigned whh1[SRPB * (HDIM / 2)];
  __shared__ float win[IDIM + STEPS];
  __shared__ float hstage[HDIM];
  __shared__ float red[SWAVES];

  const int tid = threadIdx.x, lane = tid & 63, wv = tid >> 6, blk = blockIdx.x;
  const int row = blk * SRPB + wv;

  for (int rr = 0; rr < SRPB; ++rr) {
    const float* src = p.Whh1 + (size_t)(blk * SRPB + rr) * HDIM;
    for (int u = tid; u < HDIM / 2; u += STHREADS) {
      float2 f = *reinterpret_cast<const float2*>(src + 2 * u);
      whh1[rr * (HDIM / 2) + u] = pack2(f.x, f.y);
    }
  }
  for (int i = tid; i < HDIM; i += STHREADS) hstage[i] = 0.f;
  for (int i = tid; i < IDIM; i += STHREADS) win[i] = p.x[i];

  unsigned w_ih0[8];
#pragma unroll
  for (int j = 0; j < 8; ++j) {
    const float* s = p.Wih0 + (size_t)row * IDIM + j * 128 + lane;
    w_ih0[j] = pack2(s[0], s[64]);
    PIN(w_ih0[j]);
  }
  unsigned w_hh0[32], w_ih1[32];
#pragma unroll
  for (int j = 0; j < 16; ++j) {
    float4 f;
    f = *reinterpret_cast<const float4*>(p.Whh0 + (size_t)row * HDIM + j * 256 + lane * 4);
    w_hh0[2 * j] = pack2(f.x, f.y); w_hh0[2 * j + 1] = pack2(f.z, f.w);
    PIN(w_hh0[2 * j]); PIN(w_hh0[2 * j + 1]);
    f = *reinterpret_cast<const float4*>(p.Wih1 + (size_t)row * HDIM + j * 256 + lane * 4);
    w_ih1[2 * j] = pack2(f.x, f.y); w_ih1[2 * j + 1] = pack2(f.z, f.w);
    PIN(w_ih1[2 * j]); PIN(w_ih1[2 * j + 1]);
  }
  unsigned wfcp[2];
  {
    float4 f = *reinterpret_cast<const float4*>(p.Wfc + tid * 4);
    wfcp[0] = pack2(f.x, f.y); wfcp[1] = pack2(f.z, f.w);
    PIN(wfcp[0]); PIN(wfcp[1]);
  }
  float bias0 = p.bih0[row] + p.bhh0[row];
  float bias1 = p.bih1[row] + p.bhh1[row];
  float bfc = p.bfc[0];
  PIN(bias0); PIN(bias1); PIN(bfc);

  __syncthreads();

  float p1 = 0.f;
  unsigned gen = 0;

  for (int t = 0; t < STEPS; ++t) {
    float a1 = p1;
#pragma unroll
    for (int j = 0; j < 8; ++j) {
      float v0 = win[t + j * 128 + lane];
      float v1 = win[t + j * 128 + 64 + lane];
      a1 += v0 * blo(w_ih0[j]) + v1 * bhi(w_ih0[j]);
    }
    a1 = wave_reduce(a1);
    if (lane == 0) p.h0[row] = tanhf(a1 + bias0);

    float a2 = 0.f;
    {
      const unsigned* wlp = whh1 + wv * (HDIM / 2);
#pragma unroll
      for (int j = 0; j < 16; ++j) {
        float4 v = *reinterpret_cast<const float4*>(hstage + j * 256 + lane * 4);
        unsigned c0 = wlp[j * 128 + lane * 2], c1 = wlp[j * 128 + lane * 2 + 1];
        a2 += v.x * blo(c0) + v.y * bhi(c0) + v.z * blo(c1) + v.w * bhi(c1);
      }
    }

    grid_barrier_s(p, ++gen);

    {
      float4 v = *reinterpret_cast<const float4*>(p.h0 + tid * 4);
      *reinterpret_cast<float4*>(hstage + tid * 4) = v;
    }
    __syncthreads();
    float q1 = 0.f;
#pragma unroll
    for (int j = 0; j < 16; ++j) {
      float4 v = *reinterpret_cast<const float4*>(hstage + j * 256 + lane * 4);
      a2 += v.x * blo(w_ih1[2 * j]) + v.y * bhi(w_ih1[2 * j]) +
            v.z * blo(w_ih1[2 * j + 1]) + v.w * bhi(w_ih1[2 * j + 1]);
      q1 += v.x * blo(w_hh0[2 * j]) + v.y * bhi(w_hh0[2 * j]) +
            v.z * blo(w_hh0[2 * j + 1]) + v.w * bhi(w_hh0[2 * j + 1]);
    }
    a2 = wave_reduce(a2);
    if (lane == 0) p.h1[row] = tanhf(a2 + bias1);
    p1 = q1;

    grid_barrier_s(p, ++gen);

    {
      float4 v = *reinterpret_cast<const float4*>(p.h1 + tid * 4);
      *reinterpret_cast<float4*>(hstage + tid * 4) = v;
      float part = v.x * blo(wfcp[0]) + v.y * bhi(wfcp[0]) +
                   v.z * blo(wfcp[1]) + v.w * bhi(wfcp[1]);
      part = wave_reduce(part);
      if (lane == 0) red[wv] = part;
    }
    __syncthreads();
    if (tid == 0) {
      float y = bfc;
#pragma unroll
      for (int i = 0; i < SWAVES; ++i) y += red[i];
      win[IDIM + t] = y;
      if (blk == 0) p.out[t] = y;
    }
    __syncthreads();
  }
}

// ======================= LAUNCH =======================
extern "C" void kernel_launch(void* const* d_in, const int* in_sizes, int n_in,
                              void* d_out, int out_size, void* d_ws, size_t ws_size,
                              hipStream_t stream) {
  const float* x = (const float*)d_in[0];
  const float* Wih0 = (const float*)d_in[1];
  const float* bih0 = (const float*)d_in[2];
  const float* Whh0 = (const float*)d_in[3];
  const float* bhh0 = (const float*)d_in[4];
  const float* Wih1 = (const float*)d_in[5];
  const float* bih1 = (const float*)d_in[6];
  const float* Whh1 = (const float*)d_in[7];
  const float* bhh1 = (const float*)d_in[8];
  const float* Wfc = (const float*)d_in[9];
  const float* bfc = (const float*)d_in[10];
  float* out = (float*)d_out;

  char* ws = (char*)d_ws;
  // [0,8K) h0g bf16-pairs | [8K,16K) h1g | [16K,+1.3K) fast barrier |
  // [20K,52K) safe f32 h bufs | [56K,+1.3K) safe barrier
  unsigned* h0g = (unsigned*)ws;
  unsigned* h1g = (unsigned*)(ws + 8 * 1024);
  unsigned* fbar = (unsigned*)(ws + 16 * 1024);
  float* hs = (float*)(ws + 20 * 1024);
  unsigned* sbar = (unsigned*)(ws + 56 * 1024);

  hipMemsetAsync(d_ws, 0, 64 * 1024, stream);

  int nb = 0;
  hipError_t err = hipOccupancyMaxActiveBlocksPerMultiprocessor(&nb, rnn_fast, FTHREADS, 0);

  if (err == hipSuccess && nb >= 2) {
    ParamsF p;
    p.x = x; p.Wih0 = Wih0; p.bih0 = bih0; p.Whh0 = Whh0; p.bhh0 = bhh0;
    p.Wih1 = Wih1; p.bih1 = bih1; p.Whh1 = Whh1; p.bhh1 = bhh1;
    p.Wfc = Wfc; p.bfc = bfc;
    p.h0g = h0g; p.h1g = h1g;
    p.leaf = fbar; p.root = fbar + 8 * 32; p.flag = fbar + 8 * 32 + 32;
    p.out = out;
    void* args[] = {&p};
    hipLaunchCooperativeKernel(reinterpret_cast<void*>(&rnn_fast),
                               dim3(FBLOCKS), dim3(FTHREADS), args, 0, stream);
  } else {
    ParamsS p;
    p.x = x; p.Wih0 = Wih0; p.bih0 = bih0; p.Whh0 = Whh0; p.bhh0 = bhh0;
    p.Wih1 = Wih1; p.bih1 = bih1; p.Whh1 = Whh1; p.bhh1 = bhh1;
    p.Wfc = Wfc; p.bfc = bfc;
    p.h0 = hs; p.h1 = hs + HDIM;
    p.leaf = sbar; p.root = sbar + 8 * 32; p.flag = sbar + 8 * 32 + 32;
    p.out = out;
    void* args[] = {&p};
    hipLaunchCooperativeKernel(reinterpret_cast<void*>(&rnn_safe),
                               dim3(SBLOCKS), dim3(STHREADS), args, 0, stream);
  }
}

// Round 9
// 5283.059 us; speedup vs baseline: 1.0064x; 1.0046x over previous
//
#include <hip/hip_runtime.h>

#define STEPS 96
#define HDIM 4096
#define IDIM 1024

// ---------------- fast geometry: 512 blocks x 512 threads, 2 blocks/CU ----------------
#define FBLOCKS 512
#define FTHREADS 512
#define FWAVES 8
#define FRPB 8                      // rows per block (1 per wave)
#define FGROUPS 8
#define FBPG (FBLOCKS / FGROUPS)    // 64

// ---------------- safe fallback geometry (R6, known-good) ----------------
#define SBLOCKS 256
#define STHREADS 1024
#define SWAVES 16
#define SRPB 16

#define PIN(x) asm volatile("" : "+v"(x))

// ---------- bf16 helpers ----------
__device__ inline unsigned short f2bf(float f) {
  unsigned u = __float_as_uint(f);
  u += 0x7fffu + ((u >> 16) & 1u);
  return (unsigned short)(u >> 16);
}
__device__ inline unsigned pack2(float a, float b) {
  return (unsigned)f2bf(a) | ((unsigned)f2bf(b) << 16);
}
__device__ inline float blo(unsigned p) { return __uint_as_float(p << 16); }
__device__ inline float bhi(unsigned p) { return __uint_as_float(p & 0xffff0000u); }

__device__ inline float wave_reduce(float v) {
#pragma unroll
  for (int off = 32; off > 0; off >>= 1) v += __shfl_xor(v, off);
  return v;
}

// agent-scope coherent (cache-bypassing) accessors — no fences needed around them
__device__ inline unsigned aload(const unsigned* p) {
  return __hip_atomic_load(p, __ATOMIC_RELAXED, __HIP_MEMORY_SCOPE_AGENT);
}
__device__ inline void astore(unsigned* p, unsigned v) {
  __hip_atomic_store(p, v, __ATOMIC_RELAXED, __HIP_MEMORY_SCOPE_AGENT);
}

// ======================= FAST KERNEL =======================
struct ParamsF {
  const float *x, *Wih0, *bih0, *Whh0, *bhh0, *Wih1, *bih1, *Whh1, *bhh1, *Wfc, *bfc;
  unsigned *h0g, *h1g;  // packed bf16 pairs, HDIM/2 u32 each
  unsigned *leaf, *root, *flag;
  float *out;
};

// NO-INVALIDATE grid barrier: per-thread vmcnt drain (coherent stores reach the
// MALL), relaxed agent atomics for arrive/spin, no __threadfence anywhere
// => L2 contents (weights, stack) survive across barriers.
__device__ inline void gbar_f(const ParamsF& p, unsigned gen) {
  asm volatile("s_waitcnt vmcnt(0)" ::: "memory");
  __syncthreads();
  if (threadIdx.x == 0) {
    const int g = blockIdx.x & (FGROUPS - 1);
    unsigned prev = __hip_atomic_fetch_add(p.leaf + g * 32, 1u, __ATOMIC_RELAXED,
                                           __HIP_MEMORY_SCOPE_AGENT);
    if (prev == gen * FBPG - 1) {
      unsigned r = __hip_atomic_fetch_add(p.root, 1u, __ATOMIC_RELAXED,
                                          __HIP_MEMORY_SCOPE_AGENT);
      if (r == gen * FGROUPS - 1) {
        __hip_atomic_store(p.flag, gen, __ATOMIC_RELAXED, __HIP_MEMORY_SCOPE_AGENT);
      }
    }
    while (__hip_atomic_load(p.flag, __ATOMIC_RELAXED, __HIP_MEMORY_SCOPE_AGENT) < gen) {
      __builtin_amdgcn_s_sleep(1);
    }
  }
  __syncthreads();
  asm volatile("" ::: "memory");
}

// (512, 4): hard 128-VGPR budget -> 2 blocks/CU achievable (LDS 78.3KB x2 fits 160KB)
__global__ void __launch_bounds__(FTHREADS, 4) rnn_fast(ParamsF p) {
  __shared__ unsigned whh1L[FRPB * (HDIM / 2)];  // 64 KB: block's 8 W_hh1 rows, bf16 pairs
  __shared__ float win[IDIM + STEPS];            // 4.4 KB sliding window
  __shared__ unsigned hstage[HDIM / 2];          // 8 KB: current h vector, bf16 pairs
  __shared__ float red1[FWAVES];
  __shared__ float b0L[FRPB], b1L[FRPB];
  __shared__ float bfcL;

  const int tid = threadIdx.x, lane = tid & 63, wv = tid >> 6, blk = blockIdx.x;
  const int row = blk * FRPB + wv;  // this wave's row in Wih0/Whh0/Wih1/Whh1

  // ---- setup: LDS weights + window + zero hstage (h1_old = 0 at t=0) ----
  for (int idx = tid; idx < FRPB * (HDIM / 2); idx += FTHREADS) {
    const int rr = idx >> 11, i = idx & (HDIM / 2 - 1);
    float2 f = *reinterpret_cast<const float2*>(
        p.Whh1 + (size_t)(blk * FRPB + rr) * HDIM + 2 * i);
    whh1L[idx] = pack2(f.x, f.y);
  }
  for (int i = tid; i < HDIM / 2; i += FTHREADS) hstage[i] = 0u;
  for (int i = tid; i < IDIM; i += FTHREADS) win[i] = p.x[i];
  if (tid < FRPB) {
    b0L[tid] = p.bih0[blk * FRPB + tid] + p.bhh0[blk * FRPB + tid];
    b1L[tid] = p.bih1[blk * FRPB + tid] + p.bhh1[blk * FRPB + tid];
  }
  if (tid == 0) bfcL = p.bfc[0];

  // ---- setup: 76 pinned weight regs / thread ----
  unsigned w_ih0[8];
#pragma unroll
  for (int j = 0; j < 8; ++j) {
    const float* s = p.Wih0 + (size_t)row * IDIM + j * 128 + lane;
    w_ih0[j] = pack2(s[0], s[64]);
    PIN(w_ih0[j]);
  }
  unsigned w_hh0[32], w_ih1[32];
#pragma unroll
  for (int j = 0; j < 16; ++j) {
    float4 f;
    f = *reinterpret_cast<const float4*>(p.Whh0 + (size_t)row * HDIM + j * 256 + lane * 4);
    w_hh0[2 * j] = pack2(f.x, f.y); w_hh0[2 * j + 1] = pack2(f.z, f.w);
    PIN(w_hh0[2 * j]); PIN(w_hh0[2 * j + 1]);
    f = *reinterpret_cast<const float4*>(p.Wih1 + (size_t)row * HDIM + j * 256 + lane * 4);
    w_ih1[2 * j] = pack2(f.x, f.y); w_ih1[2 * j + 1] = pack2(f.z, f.w);
    PIN(w_ih1[2 * j]); PIN(w_ih1[2 * j + 1]);
  }
  unsigned wfcp[4];
  {
    float4 f = *reinterpret_cast<const float4*>(p.Wfc + tid * 8);
    wfcp[0] = pack2(f.x, f.y); wfcp[1] = pack2(f.z, f.w);
    f = *reinterpret_cast<const float4*>(p.Wfc + tid * 8 + 4);
    wfcp[2] = pack2(f.x, f.y); wfcp[3] = pack2(f.z, f.w);
    PIN(wfcp[0]); PIN(wfcp[1]); PIN(wfcp[2]); PIN(wfcp[3]);
  }

  __syncthreads();

  float p1 = 0.f;  // carried per-lane partial of Whh0 . h0_old (zero at t=0)
  unsigned gen = 0;

  for (int t = 0; t < STEPS; ++t) {
    // ---- phase 1: full-row dot Wih0 @ win[t:] + carried partial ----
    float a1 = p1;
#pragma unroll
    for (int j = 0; j < 8; ++j) {
      a1 += win[t + j * 128 + lane] * blo(w_ih0[j]) +
            win[t + j * 128 + 64 + lane] * bhi(w_ih0[j]);
    }
    a1 = wave_reduce(a1);
    if (lane == 0) red1[wv] = a1;

    // ---- slot 2 (pre-barrier): Whh1 @ h1_old, both operands LDS ----
    float a2 = 0.f;
    {
      const unsigned* wl = whh1L + wv * (HDIM / 2);
#pragma unroll
      for (int j = 0; j < 16; ++j) {
        uint2 hv = *reinterpret_cast<const uint2*>(hstage + j * 128 + lane * 2);
        uint2 wp = *reinterpret_cast<const uint2*>(wl + j * 128 + lane * 2);
        a2 += blo(wp.x) * blo(hv.x) + bhi(wp.x) * bhi(hv.x) +
              blo(wp.y) * blo(hv.y) + bhi(wp.y) * bhi(hv.y);
      }
    }

    __syncthreads();  // red1 complete, hstage(h1_old) fully consumed
    if (tid < FRPB / 2) {
      unsigned pk = pack2(tanhf(red1[2 * tid] + b0L[2 * tid]),
                          tanhf(red1[2 * tid + 1] + b0L[2 * tid + 1]));
      astore(p.h0g + blk * (FRPB / 2) + tid, pk);
    }
    gbar_f(p, ++gen);  // h0 globally visible

    // ---- phase 2: stage h0 -> LDS (coherent loads), then Wih1 @ h0 + next Whh0 partial ----
#pragma unroll
    for (int k = 0; k < (HDIM / 2) / FTHREADS; ++k)
      hstage[tid + k * FTHREADS] = aload(p.h0g + tid + k * FTHREADS);
    __syncthreads();
    float q1 = 0.f;
#pragma unroll
    for (int j = 0; j < 16; ++j) {
      uint2 hv = *reinterpret_cast<const uint2*>(hstage + j * 128 + lane * 2);
      a2 += blo(w_ih1[2 * j]) * blo(hv.x) + bhi(w_ih1[2 * j]) * bhi(hv.x) +
            blo(w_ih1[2 * j + 1]) * blo(hv.y) + bhi(w_ih1[2 * j + 1]) * bhi(hv.y);
      q1 += blo(w_hh0[2 * j]) * blo(hv.x) + bhi(w_hh0[2 * j]) * bhi(hv.x) +
            blo(w_hh0[2 * j + 1]) * blo(hv.y) + bhi(w_hh0[2 * j + 1]) * bhi(hv.y);
    }
    a2 = wave_reduce(a2);
    if (lane == 0) red1[wv] = a2;
    p1 = q1;
    __syncthreads();
    if (tid < FRPB / 2) {
      unsigned pk = pack2(tanhf(red1[2 * tid] + b1L[2 * tid]),
                          tanhf(red1[2 * tid + 1] + b1L[2 * tid + 1]));
      astore(p.h1g + blk * (FRPB / 2) + tid, pk);
    }
    gbar_f(p, ++gen);  // h1 globally visible

    // ---- phase 3: stage h1 -> hstage (doubles as next step's h1_old); FC dot ----
#pragma unroll
    for (int k = 0; k < (HDIM / 2) / FTHREADS; ++k)
      hstage[tid + k * FTHREADS] = aload(p.h1g + tid + k * FTHREADS);
    __syncthreads();
    {
      uint2 ha = *reinterpret_cast<const uint2*>(hstage + tid * 4);
      uint2 hb = *reinterpret_cast<const uint2*>(hstage + tid * 4 + 2);
      float part = blo(wfcp[0]) * blo(ha.x) + bhi(wfcp[0]) * bhi(ha.x) +
                   blo(wfcp[1]) * blo(ha.y) + bhi(wfcp[1]) * bhi(ha.y) +
                   blo(wfcp[2]) * blo(hb.x) + bhi(wfcp[2]) * bhi(hb.x) +
                   blo(wfcp[3]) * blo(hb.y) + bhi(wfcp[3]) * bhi(hb.y);
      part = wave_reduce(part);
      if (lane == 0) red1[wv] = part;
    }
    __syncthreads();
    if (tid == 0) {
      float y = bfcL;
#pragma unroll
      for (int i = 0; i < FWAVES; ++i) y += red1[i];
      win[IDIM + t] = y;
      if (blk == 0) p.out[t] = y;
    }
    __syncthreads();
  }
}

// ======================= SAFE FALLBACK (R6, known-good 5.3ms) =======================
struct ParamsS {
  const float *x, *Wih0, *bih0, *Whh0, *bhh0, *Wih1, *bih1, *Whh1, *bhh1, *Wfc, *bfc;
  float *h0, *h1;
  unsigned *leaf, *root, *flag;
  float *out;
};

__device__ inline void grid_barrier_s(const ParamsS& p, unsigned gen) {
  __syncthreads();
  if (threadIdx.x == 0) {
    __threadfence();
    const int g = blockIdx.x & 7;
    unsigned prev = __hip_atomic_fetch_add(p.leaf + g * 32, 1u, __ATOMIC_RELAXED,
                                           __HIP_MEMORY_SCOPE_AGENT);
    if (prev == gen * (SBLOCKS / 8) - 1) {
      unsigned r = __hip_atomic_fetch_add(p.root, 1u, __ATOMIC_RELAXED,
                                          __HIP_MEMORY_SCOPE_AGENT);
      if (r == gen * 8 - 1) {
        __hip_atomic_store(p.flag, gen, __ATOMIC_RELEASE, __HIP_MEMORY_SCOPE_AGENT);
      }
    }
    while (__hip_atomic_load(p.flag, __ATOMIC_RELAXED, __HIP_MEMORY_SCOPE_AGENT) < gen) {
      __builtin_amdgcn_s_sleep(1);
    }
    __threadfence();
  }
  __syncthreads();
}

__global__ void __launch_bounds__(STHREADS) rnn_safe(ParamsS p) {
  __shared__ unsigned whh1[SRPB * (HDIM / 2)];
  __shared__ float win[IDIM + STEPS];
  __shared__ float hstage[HDIM];
  __shared__ float red[SWAVES];

  const int tid = threadIdx.x, lane = tid & 63, wv = tid >> 6, blk = blockIdx.x;
  const int row = blk * SRPB + wv;

  for (int rr = 0; rr < SRPB; ++rr) {
    const float* src = p.Whh1 + (size_t)(blk * SRPB + rr) * HDIM;
    for (int u = tid; u < HDIM / 2; u += STHREADS) {
      float2 f = *reinterpret_cast<const float2*>(src + 2 * u);
      whh1[rr * (HDIM / 2) + u] = pack2(f.x, f.y);
    }
  }
  for (int i = tid; i < HDIM; i += STHREADS) hstage[i] = 0.f;
  for (int i = tid; i < IDIM; i += STHREADS) win[i] = p.x[i];

  unsigned w_ih0[8];
#pragma unroll
  for (int j = 0; j < 8; ++j) {
    const float* s = p.Wih0 + (size_t)row * IDIM + j * 128 + lane;
    w_ih0[j] = pack2(s[0], s[64]);
    PIN(w_ih0[j]);
  }
  unsigned w_hh0[32], w_ih1[32];
#pragma unroll
  for (int j = 0; j < 16; ++j) {
    float4 f;
    f = *reinterpret_cast<const float4*>(p.Whh0 + (size_t)row * HDIM + j * 256 + lane * 4);
    w_hh0[2 * j] = pack2(f.x, f.y); w_hh0[2 * j + 1] = pack2(f.z, f.w);
    PIN(w_hh0[2 * j]); PIN(w_hh0[2 * j + 1]);
    f = *reinterpret_cast<const float4*>(p.Wih1 + (size_t)row * HDIM + j * 256 + lane * 4);
    w_ih1[2 * j] = pack2(f.x, f.y); w_ih1[2 * j + 1] = pack2(f.z, f.w);
    PIN(w_ih1[2 * j]); PIN(w_ih1[2 * j + 1]);
  }
  unsigned wfcp[2];
  {
    float4 f = *reinterpret_cast<const float4*>(p.Wfc + tid * 4);
    wfcp[0] = pack2(f.x, f.y); wfcp[1] = pack2(f.z, f.w);
    PIN(wfcp[0]); PIN(wfcp[1]);
  }
  float bias0 = p.bih0[row] + p.bhh0[row];
  float bias1 = p.bih1[row] + p.bhh1[row];
  float bfc = p.bfc[0];
  PIN(bias0); PIN(bias1); PIN(bfc);

  __syncthreads();

  float p1 = 0.f;
  unsigned gen = 0;

  for (int t = 0; t < STEPS; ++t) {
    float a1 = p1;
#pragma unroll
    for (int j = 0; j < 8; ++j) {
      float v0 = win[t + j * 128 + lane];
      float v1 = win[t + j * 128 + 64 + lane];
      a1 += v0 * blo(w_ih0[j]) + v1 * bhi(w_ih0[j]);
    }
    a1 = wave_reduce(a1);
    if (lane == 0) p.h0[row] = tanhf(a1 + bias0);

    float a2 = 0.f;
    {
      const unsigned* wlp = whh1 + wv * (HDIM / 2);
#pragma unroll
      for (int j = 0; j < 16; ++j) {
        float4 v = *reinterpret_cast<const float4*>(hstage + j * 256 + lane * 4);
        unsigned c0 = wlp[j * 128 + lane * 2], c1 = wlp[j * 128 + lane * 2 + 1];
        a2 += v.x * blo(c0) + v.y * bhi(c0) + v.z * blo(c1) + v.w * bhi(c1);
      }
    }

    grid_barrier_s(p, ++gen);

    {
      float4 v = *reinterpret_cast<const float4*>(p.h0 + tid * 4);
      *reinterpret_cast<float4*>(hstage + tid * 4) = v;
    }
    __syncthreads();
    float q1 = 0.f;
#pragma unroll
    for (int j = 0; j < 16; ++j) {
      float4 v = *reinterpret_cast<const float4*>(hstage + j * 256 + lane * 4);
      a2 += v.x * blo(w_ih1[2 * j]) + v.y * bhi(w_ih1[2 * j]) +
            v.z * blo(w_ih1[2 * j + 1]) + v.w * bhi(w_ih1[2 * j + 1]);
      q1 += v.x * blo(w_hh0[2 * j]) + v.y * bhi(w_hh0[2 * j]) +
            v.z * blo(w_hh0[2 * j + 1]) + v.w * bhi(w_hh0[2 * j + 1]);
    }
    a2 = wave_reduce(a2);
    if (lane == 0) p.h1[row] = tanhf(a2 + bias1);
    p1 = q1;

    grid_barrier_s(p, ++gen);

    {
      float4 v = *reinterpret_cast<const float4*>(p.h1 + tid * 4);
      *reinterpret_cast<float4*>(hstage + tid * 4) = v;
      float part = v.x * blo(wfcp[0]) + v.y * bhi(wfcp[0]) +
                   v.z * blo(wfcp[1]) + v.w * bhi(wfcp[1]);
      part = wave_reduce(part);
      if (lane == 0) red[wv] = part;
    }
    __syncthreads();
    if (tid == 0) {
      float y = bfc;
#pragma unroll
      for (int i = 0; i < SWAVES; ++i) y += red[i];
      win[IDIM + t] = y;
      if (blk == 0) p.out[t] = y;
    }
    __syncthreads();
  }
}

// ======================= LAUNCH =======================
extern "C" void kernel_launch(void* const* d_in, const int* in_sizes, int n_in,
                              void* d_out, int out_size, void* d_ws, size_t ws_size,
                              hipStream_t stream) {
  const float* x = (const float*)d_in[0];
  const float* Wih0 = (const float*)d_in[1];
  const float* bih0 = (const float*)d_in[2];
  const float* Whh0 = (const float*)d_in[3];
  const float* bhh0 = (const float*)d_in[4];
  const float* Wih1 = (const float*)d_in[5];
  const float* bih1 = (const float*)d_in[6];
  const float* Whh1 = (const float*)d_in[7];
  const float* bhh1 = (const float*)d_in[8];
  const float* Wfc = (const float*)d_in[9];
  const float* bfc = (const float*)d_in[10];
  float* out = (float*)d_out;

  char* ws = (char*)d_ws;
  // [0,8K) h0g bf16-pairs | [8K,16K) h1g | [16K,+1.3K) fast barrier |
  // [20K,52K) safe f32 h bufs | [56K,+1.3K) safe barrier
  unsigned* h0g = (unsigned*)ws;
  unsigned* h1g = (unsigned*)(ws + 8 * 1024);
  unsigned* fbar = (unsigned*)(ws + 16 * 1024);
  float* hs = (float*)(ws + 20 * 1024);
  unsigned* sbar = (unsigned*)(ws + 56 * 1024);

  hipMemsetAsync(d_ws, 0, 64 * 1024, stream);

  int nb = 0;
  hipError_t err = hipOccupancyMaxActiveBlocksPerMultiprocessor(&nb, rnn_fast, FTHREADS, 0);

  if (err == hipSuccess && nb >= 2) {
    ParamsF p;
    p.x = x; p.Wih0 = Wih0; p.bih0 = bih0; p.Whh0 = Whh0; p.bhh0 = bhh0;
    p.Wih1 = Wih1; p.bih1 = bih1; p.Whh1 = Whh1; p.bhh1 = bhh1;
    p.Wfc = Wfc; p.bfc = bfc;
    p.h0g = h0g; p.h1g = h1g;
    p.leaf = fbar; p.root = fbar + 8 * 32; p.flag = fbar + 8 * 32 + 32;
    p.out = out;
    void* args[] = {&p};
    hipLaunchCooperativeKernel(reinterpret_cast<void*>(&rnn_fast),
                               dim3(FBLOCKS), dim3(FTHREADS), args, 0, stream);
  } else {
    ParamsS p;
    p.x = x; p.Wih0 = Wih0; p.bih0 = bih0; p.Whh0 = Whh0; p.bhh0 = bhh0;
    p.Wih1 = Wih1; p.bih1 = bih1; p.Whh1 = Whh1; p.bhh1 = bhh1;
    p.Wfc = Wfc; p.bfc = bfc;
    p.h0 = hs; p.h1 = hs + HDIM;
    p.leaf = sbar; p.root = sbar + 8 * 32; p.flag = sbar + 8 * 32 + 32;
    p.out = out;
    void* args[] = {&p};
    hipLaunchCooperativeKernel(reinterpret_cast<void*>(&rnn_safe),
                               dim3(SBLOCKS), dim3(STHREADS), args, 0, stream);
  }
}

// Round 10
// 4392.214 us; speedup vs baseline: 1.2105x; 1.2028x over previous
//
#include <hip/hip_runtime.h>

#define STEPS 96
#define HDIM 4096
#define IDIM 1024
#define BLOCKS 256
#define THREADS 512
#define WAVES 8
#define RPB 16                    // rows per block (2 per wave)
#define GROUPS 8
#define BPG (BLOCKS / GROUPS)     // 32

#define PIN(x) asm volatile("" : "+v"(x))

// ---------- bf16 helpers ----------
__device__ inline unsigned short f2bf(float f) {
  unsigned u = __float_as_uint(f);
  u += 0x7fffu + ((u >> 16) & 1u);
  return (unsigned short)(u >> 16);
}
__device__ inline unsigned pack2(float a, float b) {
  return (unsigned)f2bf(a) | ((unsigned)f2bf(b) << 16);
}
__device__ inline float blo(unsigned p) { return __uint_as_float(p << 16); }
__device__ inline float bhi(unsigned p) { return __uint_as_float(p & 0xffff0000u); }

__device__ inline float wave_reduce(float v) {
#pragma unroll
  for (int off = 32; off > 0; off >>= 1) v += __shfl_xor(v, off);
  return v;
}

// agent-scope coherent accessors (validated R9: correct h exchange, no fences)
__device__ inline unsigned aload(const unsigned* p) {
  return __hip_atomic_load(p, __ATOMIC_RELAXED, __HIP_MEMORY_SCOPE_AGENT);
}
__device__ inline void astore(unsigned* p, unsigned v) {
  __hip_atomic_store(p, v, __ATOMIC_RELAXED, __HIP_MEMORY_SCOPE_AGENT);
}

struct Params {
  const float *x, *Wih0, *bih0, *Whh0, *bhh0, *Wih1, *bih1, *Whh1, *bhh1, *Wfc, *bfc;
  unsigned *h0g, *h1g;  // packed bf16 pairs, HDIM/2 u32 each
  unsigned *leaf, *root, *flag;
  float *out;
};

// NO-INVALIDATE grid barrier (validated R9): vmcnt drain + relaxed agent atomics,
// no __threadfence => L2 (weights/stack) survives across barriers.
__device__ inline void gbar(const Params& p, unsigned gen) {
  asm volatile("s_waitcnt vmcnt(0)" ::: "memory");
  __syncthreads();
  if (threadIdx.x == 0) {
    const int g = blockIdx.x & (GROUPS - 1);
    unsigned prev = __hip_atomic_fetch_add(p.leaf + g * 32, 1u, __ATOMIC_RELAXED,
                                           __HIP_MEMORY_SCOPE_AGENT);
    if (prev == gen * BPG - 1) {
      unsigned r = __hip_atomic_fetch_add(p.root, 1u, __ATOMIC_RELAXED,
                                          __HIP_MEMORY_SCOPE_AGENT);
      if (r == gen * GROUPS - 1) {
        __hip_atomic_store(p.flag, gen, __ATOMIC_RELAXED, __HIP_MEMORY_SCOPE_AGENT);
      }
    }
    while (__hip_atomic_load(p.flag, __ATOMIC_RELAXED, __HIP_MEMORY_SCOPE_AGENT) < gen) {
      __builtin_amdgcn_s_sleep(1);
    }
  }
  __syncthreads();
  asm volatile("" ::: "memory");
}

// (512, 1): 1 block/CU min -> 2 waves/EU target -> 256-VGPR budget (R3-law)
__global__ void __launch_bounds__(THREADS, 1) rnn_kernel(Params p) {
  __shared__ unsigned whh1L[RPB * (HDIM / 2)];  // 128 KB: block's 16 W_hh1 rows
  __shared__ float win[IDIM + STEPS];           // 4.4 KB sliding window
  __shared__ unsigned hstage[HDIM / 2];         // 8 KB current h (bf16 pairs)
  __shared__ float red1[WAVES];

  const int tid = threadIdx.x, lane = tid & 63, wv = tid >> 6, blk = blockIdx.x;
  const int r0 = blk * RPB + wv * 2;  // wave owns rows r0, r0+1 of every matrix
  const int r1 = r0 + 1;

  // ---- setup: LDS W_hh1 + window + zero hstage (h1_old = 0 at t=0) ----
  for (int idx = tid; idx < RPB * (HDIM / 2); idx += THREADS) {
    const int rr = idx >> 11, i = idx & (HDIM / 2 - 1);
    float2 f = *reinterpret_cast<const float2*>(
        p.Whh1 + (size_t)(blk * RPB + rr) * HDIM + 2 * i);
    whh1L[idx] = pack2(f.x, f.y);
  }
  for (int i = tid; i < HDIM / 2; i += THREADS) hstage[i] = 0u;
  for (int i = tid; i < IDIM; i += THREADS) win[i] = p.x[i];

  // ---- setup: 148 pinned weight u32 / thread ----
  unsigned wA_ih0[8], wB_ih0[8];
#pragma unroll
  for (int j = 0; j < 8; ++j) {
    const float* sA = p.Wih0 + (size_t)r0 * IDIM + j * 128 + lane;
    const float* sB = p.Wih0 + (size_t)r1 * IDIM + j * 128 + lane;
    wA_ih0[j] = pack2(sA[0], sA[64]); PIN(wA_ih0[j]);
    wB_ih0[j] = pack2(sB[0], sB[64]); PIN(wB_ih0[j]);
  }
  unsigned wA_hh0[32], wB_hh0[32], wA_ih1[32], wB_ih1[32];
#pragma unroll
  for (int j = 0; j < 16; ++j) {
    float4 f;
    f = *reinterpret_cast<const float4*>(p.Whh0 + (size_t)r0 * HDIM + j * 256 + lane * 4);
    wA_hh0[2 * j] = pack2(f.x, f.y); wA_hh0[2 * j + 1] = pack2(f.z, f.w);
    PIN(wA_hh0[2 * j]); PIN(wA_hh0[2 * j + 1]);
    f = *reinterpret_cast<const float4*>(p.Whh0 + (size_t)r1 * HDIM + j * 256 + lane * 4);
    wB_hh0[2 * j] = pack2(f.x, f.y); wB_hh0[2 * j + 1] = pack2(f.z, f.w);
    PIN(wB_hh0[2 * j]); PIN(wB_hh0[2 * j + 1]);
    f = *reinterpret_cast<const float4*>(p.Wih1 + (size_t)r0 * HDIM + j * 256 + lane * 4);
    wA_ih1[2 * j] = pack2(f.x, f.y); wA_ih1[2 * j + 1] = pack2(f.z, f.w);
    PIN(wA_ih1[2 * j]); PIN(wA_ih1[2 * j + 1]);
    f = *reinterpret_cast<const float4*>(p.Wih1 + (size_t)r1 * HDIM + j * 256 + lane * 4);
    wB_ih1[2 * j] = pack2(f.x, f.y); wB_ih1[2 * j + 1] = pack2(f.z, f.w);
    PIN(wB_ih1[2 * j]); PIN(wB_ih1[2 * j + 1]);
  }
  unsigned wfcp[4];
  {
    float4 f = *reinterpret_cast<const float4*>(p.Wfc + tid * 8);
    wfcp[0] = pack2(f.x, f.y); wfcp[1] = pack2(f.z, f.w);
    f = *reinterpret_cast<const float4*>(p.Wfc + tid * 8 + 4);
    wfcp[2] = pack2(f.x, f.y); wfcp[3] = pack2(f.z, f.w);
    PIN(wfcp[0]); PIN(wfcp[1]); PIN(wfcp[2]); PIN(wfcp[3]);
  }
  float b0A = p.bih0[r0] + p.bhh0[r0], b0B = p.bih0[r1] + p.bhh0[r1];
  float b1A = p.bih1[r0] + p.bhh1[r0], b1B = p.bih1[r1] + p.bhh1[r1];
  float bfc = p.bfc[0];
  PIN(b0A); PIN(b0B); PIN(b1A); PIN(b1B); PIN(bfc);

  __syncthreads();

  float p1A = 0.f, p1B = 0.f;  // carried Whh0 . h0_old partials (zero at t=0)
  unsigned gen = 0;

  for (int t = 0; t < STEPS; ++t) {
    // ---- phase 1: h0 rows = tanh(Wih0 @ win[t:] + carried + bias) ----
    float a1A = p1A, a1B = p1B;
#pragma unroll
    for (int j = 0; j < 8; ++j) {
      float v0 = win[t + j * 128 + lane];
      float v1 = win[t + j * 128 + 64 + lane];
      a1A += v0 * blo(wA_ih0[j]) + v1 * bhi(wA_ih0[j]);
      a1B += v0 * blo(wB_ih0[j]) + v1 * bhi(wB_ih0[j]);
    }
    a1A = wave_reduce(a1A);
    a1B = wave_reduce(a1B);
    if (lane == 0)
      astore(p.h0g + blk * WAVES + wv, pack2(tanhf(a1A + b0A), tanhf(a1B + b0B)));

    // ---- slot 2 (pre-barrier): Whh1 @ h1_old, both operands in LDS ----
    float a2A = 0.f, a2B = 0.f;
    {
      const unsigned* wl0 = whh1L + (wv * 2) * (HDIM / 2);
      const unsigned* wl1 = wl0 + (HDIM / 2);
#pragma unroll
      for (int j = 0; j < 16; ++j) {
        uint2 hv = *reinterpret_cast<const uint2*>(hstage + j * 128 + lane * 2);
        uint2 wx = *reinterpret_cast<const uint2*>(wl0 + j * 128 + lane * 2);
        uint2 wy = *reinterpret_cast<const uint2*>(wl1 + j * 128 + lane * 2);
        float h0 = blo(hv.x), h1 = bhi(hv.x), h2 = blo(hv.y), h3 = bhi(hv.y);
        a2A += blo(wx.x) * h0 + bhi(wx.x) * h1 + blo(wx.y) * h2 + bhi(wx.y) * h3;
        a2B += blo(wy.x) * h0 + bhi(wy.x) * h1 + blo(wy.y) * h2 + bhi(wy.y) * h3;
      }
    }

    gbar(p, ++gen);  // h0 globally visible; hstage(h1_old) consumed

    // ---- phase 2: hstage <- h0; += Wih1 @ h0; next-step Whh0 @ h0 partials ----
#pragma unroll
    for (int k = 0; k < (HDIM / 2) / THREADS; ++k)
      hstage[tid + k * THREADS] = aload(p.h0g + tid + k * THREADS);
    __syncthreads();
    float q1A = 0.f, q1B = 0.f;
#pragma unroll
    for (int j = 0; j < 16; ++j) {
      uint2 hv = *reinterpret_cast<const uint2*>(hstage + j * 128 + lane * 2);
      float h0 = blo(hv.x), h1 = bhi(hv.x), h2 = blo(hv.y), h3 = bhi(hv.y);
      a2A += blo(wA_ih1[2 * j]) * h0 + bhi(wA_ih1[2 * j]) * h1 +
             blo(wA_ih1[2 * j + 1]) * h2 + bhi(wA_ih1[2 * j + 1]) * h3;
      a2B += blo(wB_ih1[2 * j]) * h0 + bhi(wB_ih1[2 * j]) * h1 +
             blo(wB_ih1[2 * j + 1]) * h2 + bhi(wB_ih1[2 * j + 1]) * h3;
      q1A += blo(wA_hh0[2 * j]) * h0 + bhi(wA_hh0[2 * j]) * h1 +
             blo(wA_hh0[2 * j + 1]) * h2 + bhi(wA_hh0[2 * j + 1]) * h3;
      q1B += blo(wB_hh0[2 * j]) * h0 + bhi(wB_hh0[2 * j]) * h1 +
             blo(wB_hh0[2 * j + 1]) * h2 + bhi(wB_hh0[2 * j + 1]) * h3;
    }
    a2A = wave_reduce(a2A);
    a2B = wave_reduce(a2B);
    if (lane == 0)
      astore(p.h1g + blk * WAVES + wv, pack2(tanhf(a2A + b1A), tanhf(a2B + b1B)));
    p1A = q1A;
    p1B = q1B;

    gbar(p, ++gen);  // h1 globally visible

    // ---- phase 3: hstage <- h1 (doubles as next h1_old); FC dot; append ----
#pragma unroll
    for (int k = 0; k < (HDIM / 2) / THREADS; ++k)
      hstage[tid + k * THREADS] = aload(p.h1g + tid + k * THREADS);
    __syncthreads();
    {
      uint2 ha = *reinterpret_cast<const uint2*>(hstage + tid * 4);
      uint2 hb = *reinterpret_cast<const uint2*>(hstage + tid * 4 + 2);
      float part = blo(wfcp[0]) * blo(ha.x) + bhi(wfcp[0]) * bhi(ha.x) +
                   blo(wfcp[1]) * blo(ha.y) + bhi(wfcp[1]) * bhi(ha.y) +
                   blo(wfcp[2]) * blo(hb.x) + bhi(wfcp[2]) * bhi(hb.x) +
                   blo(wfcp[3]) * blo(hb.y) + bhi(wfcp[3]) * bhi(hb.y);
      part = wave_reduce(part);
      if (lane == 0) red1[wv] = part;
    }
    __syncthreads();
    if (tid == 0) {
      float y = bfc;
#pragma unroll
      for (int i = 0; i < WAVES; ++i) y += red1[i];
      win[IDIM + t] = y;
      if (blk == 0) p.out[t] = y;
    }
    __syncthreads();
  }
}

extern "C" void kernel_launch(void* const* d_in, const int* in_sizes, int n_in,
                              void* d_out, int out_size, void* d_ws, size_t ws_size,
                              hipStream_t stream) {
  Params p;
  p.x = (const float*)d_in[0];
  p.Wih0 = (const float*)d_in[1];
  p.bih0 = (const float*)d_in[2];
  p.Whh0 = (const float*)d_in[3];
  p.bhh0 = (const float*)d_in[4];
  p.Wih1 = (const float*)d_in[5];
  p.bih1 = (const float*)d_in[6];
  p.Whh1 = (const float*)d_in[7];
  p.bhh1 = (const float*)d_in[8];
  p.Wfc = (const float*)d_in[9];
  p.bfc = (const float*)d_in[10];
  p.out = (float*)d_out;

  char* ws = (char*)d_ws;
  // [0,8K) h0g bf16-pairs | [8K,16K) h1g | [16K,+1.3K) barrier state
  p.h0g = (unsigned*)ws;
  p.h1g = (unsigned*)(ws + 8 * 1024);
  unsigned* bar = (unsigned*)(ws + 16 * 1024);
  p.leaf = bar;
  p.root = bar + 8 * 32;
  p.flag = bar + 8 * 32 + 32;

  // zero barrier state every call (graph-replay safe); h bufs written before read
  hipMemsetAsync(bar, 0, (8 * 32 + 64) * sizeof(unsigned), stream);

  void* args[] = {&p};
  hipLaunchCooperativeKernel(reinterpret_cast<void*>(&rnn_kernel),
                             dim3(BLOCKS), dim3(THREADS), args, 0, stream);
}